// Round 6
// baseline (455.935 us; speedup 1.0000x reference)
//
#include <hip/hip_runtime.h>

// PointConv (kernel=stride=2x2, pad=0, grouping=C): per-location GEMM
//   out_l(32x256) = P_l(32x256) @ W_l(256x256) + bias[:,l]
// B=32, C=64, H=W=64, L=1024, n=256. fp32 in/out, bf16 MFMA inside.
// R7 = R6 with the OOB addressing bug fixed (quad*8 row offset was added
// twice -> W rows up to 272 -> device fault). Theory unchanged:
// depth hypothesis falsified (R5); surviving model is per-wave
// outstanding-miss quota -> BW scales with RESIDENT WAVES. This version
// runs 32 waves/CU: each l split into 2 blocks by p-half (disjoint 128KB
// W each), register W path (sinking harmless under wave-count model),
// no W-LDS, 17KB A-tile + one barrier, acc 2x2, launch_bounds(256,8)
// -> 8 blocks/CU. 2048 blocks = exactly 8/CU. Cost: x fetched 2x (+33MB).

#define B_  32
#define C_  64
#define H_  64
#define W_  64
#define L_  1024
#define N_  256
#define SA  264   // A pitch (ushorts): 256+8

typedef __bf16 bf16x8 __attribute__((ext_vector_type(8)));
typedef float  f32x4  __attribute__((ext_vector_type(4)));

__device__ __forceinline__ unsigned short f2bf(float f) {
  unsigned int u = __builtin_bit_cast(unsigned int, f);
  u += 0x7FFFu + ((u >> 16) & 1u);          // RNE
  return (unsigned short)(u >> 16);
}

__global__ __launch_bounds__(256, 8) void pointconv_kernel(
    const float* __restrict__ x, const float* __restrict__ wgt,
    const float* __restrict__ bias, float* __restrict__ out) {
  __shared__ unsigned short A[B_ * SA];     // patches bf16 [b][n], 16.9KB

  const int bid = blockIdx.x;               // 2048 blocks
  // XCD swizzle: xcd = bid&7 owns l in [xcd*128, xcd*128+128), both halves
  // of an l are consecutive dispatches on the same XCD (x reads L2-merge).
  const int l    = ((bid & 7) << 7) | (bid >> 4);
  const int half = (bid >> 3) & 1;          // p in [half*128, half*128+128)
  const int ph = l >> 5, pw = l & 31;
  const int h0 = ph * 2, w0 = pw * 2;
  const int tid  = threadIdx.x;
  const int lane = tid & 63;
  const int wv   = tid >> 6;                // wave owns 32 p-cols
  const int col  = lane & 15;
  const int quad = lane >> 4;

  const int pbase = half * 128 + wv * 32;
  const float* __restrict__ wl = wgt + (size_t)l * (N_ * N_);
  // Per-lane W base in B-fragment layout:
  //   row = quad*8 (here) + j (in-loop) + 32*s (in-loop); col = pbase+col+nt*16
  const float* __restrict__ wp = wl + (quad * 8) * N_ + pbase + col;

  // ---- Phase 1: unfold x[b, c, 2ph+kh, 2pw+kw] -> A[b][n = c*4 + kh*2 + kw]
  {
    const int b  = tid & 31;
    const int c0 = tid >> 5;
#pragma unroll
    for (int i = 0; i < 8; ++i) {
      const int c = c0 + i * 8;
      const float* px = x + (((b * C_ + c) * H_ + h0) * W_ + w0);
      float2 v0 = *(const float2*)px;
      float2 v1 = *(const float2*)(px + W_);
      ushort4 q;
      q.x = f2bf(v0.x); q.y = f2bf(v0.y);
      q.z = f2bf(v1.x); q.w = f2bf(v1.y);
      *(ushort4*)&A[b * SA + c * 4] = q;
    }
  }

  // ---- bias init (C/D: col -> p, quad*4+reg -> b)
  f32x4 acc[2][2];
#pragma unroll
  for (int nt = 0; nt < 2; ++nt) {
    const float bv = bias[(pbase + nt * 16 + col) * L_ + l];
#pragma unroll
    for (int mt = 0; mt < 2; ++mt) {
      acc[mt][nt][0] = bv; acc[mt][nt][1] = bv;
      acc[mt][nt][2] = bv; acc[mt][nt][3] = bv;
    }
  }

  __syncthreads();   // A ready — the only barrier

  // ---- K-loop: 8 slabs of 32, register W path, waves fully independent.
  // W row for lane = s*32 + quad*8 + j (quad*8 baked into wp).
#pragma unroll
  for (int s = 0; s < 8; ++s) {
    bf16x8 af0 = *(const bf16x8*)&A[col * SA + s * 32 + quad * 8];
    bf16x8 af1 = *(const bf16x8*)&A[(16 + col) * SA + s * 32 + quad * 8];
#pragma unroll
    for (int nt = 0; nt < 2; ++nt) {
      const float* wr = wp + (size_t)(s * 32) * N_ + nt * 16;
      union { unsigned short u[8]; bf16x8 v; } bu;
#pragma unroll
      for (int j = 0; j < 8; ++j)
        bu.u[j] = f2bf(wr[j * N_]);
      acc[0][nt] = __builtin_amdgcn_mfma_f32_16x16x32_bf16(af0, bu.v,
                                                           acc[0][nt], 0, 0, 0);
      acc[1][nt] = __builtin_amdgcn_mfma_f32_16x16x32_bf16(af1, bu.v,
                                                           acc[1][nt], 0, 0, 0);
    }
  }

  // ---- Epilogue: fold. p -> (c=p>>2, kh=(p>>1)&1, kw=p&1)
#pragma unroll
  for (int mt = 0; mt < 2; ++mt) {
#pragma unroll
    for (int nt = 0; nt < 2; ++nt) {
      const int p  = pbase + nt * 16 + col;
      const int c  = p >> 2;
      const int kh = (p >> 1) & 1;
      const int kw = p & 1;
      float* po = out + (((c * H_) + h0 + kh) * W_ + w0 + kw);
#pragma unroll
      for (int r = 0; r < 4; ++r) {
        const int b = mt * 16 + quad * 4 + r;
        po[b * (C_ * H_ * W_)] = acc[mt][nt][r];
      }
    }
  }
}

extern "C" void kernel_launch(void* const* d_in, const int* in_sizes, int n_in,
                              void* d_out, int out_size, void* d_ws, size_t ws_size,
                              hipStream_t stream) {
  const float* x    = (const float*)d_in[0];
  const float* wgt  = (const float*)d_in[1];
  const float* bias = (const float*)d_in[2];
  float* out = (float*)d_out;
  pointconv_kernel<<<dim3(2 * L_), dim3(256), 0, stream>>>(x, wgt, bias, out);
}